// Round 3
// baseline (3693.300 us; speedup 1.0000x reference)
//
#include <hip/hip_runtime.h>

#define NN 100000      // nodes
#define NE 1000000     // edges per relation
#define RR 4           // relations
#define GG 256         // graphs
#define DHID 128       // feature width (DIN == DH == 128)
#define NCLS 10        // classes
#define RN (RR * NN)   // virtual segments (r, dst)
#define NBLK ((RN + 1023) / 1024)

// ---------------------------------------------------------------- degrees ---
__global__ __launch_bounds__(256) void degree_count(const int* __restrict__ edges,
                                                    int* __restrict__ cnt_out,
                                                    int* __restrict__ cnt_in) {
    int t = blockIdx.x * 256 + threadIdx.x;
    if (t >= RR * NE) return;
    int r = t / NE;
    int e = t - r * NE;
    const int* base = edges + (size_t)r * 2 * NE;
    atomicAdd(&cnt_out[r * NN + base[e]], 1);
    atomicAdd(&cnt_in[r * NN + base[NE + e]], 1);
}

__global__ __launch_bounds__(256) void deg_to_scale(const int* __restrict__ cnt_out,
                                                    const int* __restrict__ cnt_in,
                                                    float* __restrict__ so,
                                                    float* __restrict__ si) {
    int t = blockIdx.x * 256 + threadIdx.x;
    if (t >= RN) return;
    int co = cnt_out[t], ci = cnt_in[t];
    so[t] = rsqrtf((float)(co < 1 ? 1 : co));
    si[t] = rsqrtf((float)(ci < 1 ? 1 : ci));
}

// ------------------------------------------------------------- CSR build ----
__global__ __launch_bounds__(256) void scan_partial(const int* __restrict__ cnt,
                                                    int* __restrict__ partial) {
    __shared__ int sdat[256];
    int t = threadIdx.x;
    int base = blockIdx.x * 1024 + t * 4;
    int s = 0;
    #pragma unroll
    for (int i = 0; i < 4; ++i)
        if (base + i < RN) s += cnt[base + i];
    sdat[t] = s;
    __syncthreads();
    for (int off = 128; off > 0; off >>= 1) {
        if (t < off) sdat[t] += sdat[t + off];
        __syncthreads();
    }
    if (t == 0) partial[blockIdx.x] = sdat[0];
}

__global__ __launch_bounds__(512) void scan_block(int* __restrict__ partial) {
    __shared__ int s[512];
    int t = threadIdx.x;
    s[t] = (t < NBLK) ? partial[t] : 0;
    __syncthreads();
    for (int off = 1; off < 512; off <<= 1) {
        int v = (t >= off) ? s[t - off] : 0;
        __syncthreads();
        s[t] += v;
        __syncthreads();
    }
    if (t < NBLK) partial[t] = (t == 0) ? 0 : s[t - 1];
}

__global__ __launch_bounds__(256) void scan_write(const int* __restrict__ cnt,
                                                  const int* __restrict__ partial,
                                                  int* __restrict__ row_ptr,
                                                  int* __restrict__ cursor) {
    __shared__ int ssum[256];
    int t = threadIdx.x;
    int base = blockIdx.x * 1024 + t * 4;
    int c[4];
    #pragma unroll
    for (int i = 0; i < 4; ++i)
        c[i] = (base + i < RN) ? cnt[base + i] : 0;
    ssum[t] = c[0] + c[1] + c[2] + c[3];
    __syncthreads();
    for (int off = 1; off < 256; off <<= 1) {
        int v = (t >= off) ? ssum[t - off] : 0;
        __syncthreads();
        ssum[t] += v;
        __syncthreads();
    }
    int e = partial[blockIdx.x] + (t == 0 ? 0 : ssum[t - 1]);
    #pragma unroll
    for (int i = 0; i < 4; ++i) {
        if (base + i < RN) { row_ptr[base + i] = e; cursor[base + i] = e; e += c[i]; }
    }
    if (blockIdx.x == 0 && t == 0) row_ptr[RN] = RR * NE;
}

// packed edge record: .x = src index, .y = float bits of so[src]*si[dst]
__global__ __launch_bounds__(256) void fill_csr(const int* __restrict__ edges,
                                                const float* __restrict__ so,
                                                const float* __restrict__ si,
                                                int* __restrict__ cursor,
                                                int2* __restrict__ ew) {
    int t = blockIdx.x * 256 + threadIdx.x;
    if (t >= RR * NE) return;
    int r = t / NE;
    int e = t - r * NE;
    const int* eb = edges + (size_t)r * 2 * NE;
    int s = eb[e];
    int d = eb[NE + e];
    int rb = r * NN;
    float w = so[rb + s] * si[rb + d];
    int pos = atomicAdd(&cursor[rb + d], 1);
    ew[pos] = make_int2(s, __float_as_int(w));
}

// ------------------------------------------------------------- layer --------
// One kernel = one full HeteroGraphConv layer + bias + ReLU.
// 32-row tile (17KB LDS). Per relation: gather (8-deep MLP, prefolded edge
// weights) into LDS; register GEMM-accumulate acc += As @ W_r; epilogue adds
// sum_r b[r], ReLU, pure float4 store.
__global__ __launch_bounds__(256, 6) void layer_kernel(
    const float* __restrict__ hin, const int* __restrict__ row_ptr,
    const int2* __restrict__ ew, const float* __restrict__ W,
    const float* __restrict__ b, float* __restrict__ hout) {
    __shared__ float As[32 * 132];
    const int tid  = threadIdx.x;
    const int wave = tid >> 6;
    const int lane = tid & 63;
    const int rowbase = blockIdx.x * 32;

    const int rp = tid >> 3;          // 0..31 (own output row)
    const int cb = tid & 7;           // 0..7 col base

    float acc[16];
    #pragma unroll
    for (int i = 0; i < 16; ++i) acc[i] = 0.f;

    for (int r = 0; r < RR; ++r) {
        const int rbase = r * NN;
        if (r) __syncthreads();       // previous GEMM done reading As

        // ---- gather: wave owns 8 rows; all control flow wave-uniform ----
        for (int rr = 0; rr < 8; ++rr) {
            int rowLocal = wave * 8 + rr;
            int d = rowbase + rowLocal;
            float ax0 = 0.f, ay0 = 0.f, ax1 = 0.f, ay1 = 0.f;
            if (d < NN) {
                int beg = row_ptr[rbase + d];
                int end = row_ptr[rbase + d + 1];
                int j = beg;
                for (; j + 8 <= end; j += 8) {
                    int2 p[8];
                    #pragma unroll
                    for (int i = 0; i < 8; ++i) p[i] = ew[j + i];
                    float2 v[8];
                    #pragma unroll
                    for (int i = 0; i < 8; ++i)
                        v[i] = *(const float2*)&hin[(size_t)p[i].x * DHID + (lane << 1)];
                    #pragma unroll
                    for (int i = 0; i < 8; ++i) {
                        float w = __int_as_float(p[i].y);
                        if (i & 1) { ax1 = fmaf(w, v[i].x, ax1); ay1 = fmaf(w, v[i].y, ay1); }
                        else       { ax0 = fmaf(w, v[i].x, ax0); ay0 = fmaf(w, v[i].y, ay0); }
                    }
                }
                if (j + 4 <= end) {
                    int2 p[4];
                    #pragma unroll
                    for (int i = 0; i < 4; ++i) p[i] = ew[j + i];
                    float2 v[4];
                    #pragma unroll
                    for (int i = 0; i < 4; ++i)
                        v[i] = *(const float2*)&hin[(size_t)p[i].x * DHID + (lane << 1)];
                    #pragma unroll
                    for (int i = 0; i < 4; ++i) {
                        float w = __int_as_float(p[i].y);
                        if (i & 1) { ax1 = fmaf(w, v[i].x, ax1); ay1 = fmaf(w, v[i].y, ay1); }
                        else       { ax0 = fmaf(w, v[i].x, ax0); ay0 = fmaf(w, v[i].y, ay0); }
                    }
                    j += 4;
                }
                for (; j < end; ++j) {
                    int2 p = ew[j];
                    float w = __int_as_float(p.y);
                    float2 v = *(const float2*)&hin[(size_t)p.x * DHID + (lane << 1)];
                    ax0 = fmaf(w, v.x, ax0); ay0 = fmaf(w, v.y, ay0);
                }
            }
            As[rowLocal * 132 + lane * 2]     = ax0 + ax1;
            As[rowLocal * 132 + lane * 2 + 1] = ay0 + ay1;
        }
        __syncthreads();

        // ---- GEMM: acc += As @ W_r (one output row per thread) ----
        const float4* Wv = (const float4*)(W + (size_t)r * DHID * DHID);
        for (int k = 0; k < 128; k += 4) {
            float4 a = *(const float4*)&As[rp * 132 + k];
            float x[4] = {a.x, a.y, a.z, a.w};
            #pragma unroll
            for (int kk = 0; kk < 4; ++kk) {
                #pragma unroll
                for (int g = 0; g < 4; ++g) {
                    float4 w = Wv[(k + kk) * 32 + cb + 8 * g];
                    acc[4 * g + 0] = fmaf(x[kk], w.x, acc[4 * g + 0]);
                    acc[4 * g + 1] = fmaf(x[kk], w.y, acc[4 * g + 1]);
                    acc[4 * g + 2] = fmaf(x[kk], w.z, acc[4 * g + 2]);
                    acc[4 * g + 3] = fmaf(x[kk], w.w, acc[4 * g + 3]);
                }
            }
        }
    }

    // ---- epilogue: + sum_r b[r], ReLU, store ----
    int rowg = rowbase + rp;
    if (rowg < NN) {
        #pragma unroll
        for (int g = 0; g < 4; ++g) {
            int col = cb * 4 + 32 * g;
            float4 bs  = *(const float4*)&b[0 * DHID + col];
            float4 bv1 = *(const float4*)&b[1 * DHID + col];
            float4 bv2 = *(const float4*)&b[2 * DHID + col];
            float4 bv3 = *(const float4*)&b[3 * DHID + col];
            float4 o;
            o.x = fmaxf(acc[4 * g + 0] + bs.x + bv1.x + bv2.x + bv3.x, 0.f);
            o.y = fmaxf(acc[4 * g + 1] + bs.y + bv1.y + bv2.y + bv3.y, 0.f);
            o.z = fmaxf(acc[4 * g + 2] + bs.z + bv1.z + bv2.z + bv3.z, 0.f);
            o.w = fmaxf(acc[4 * g + 3] + bs.w + bv1.w + bv2.w + bv3.w, 0.f);
            *(float4*)&hout[(size_t)rowg * DHID + col] = o;
        }
    }
}

// ---------------------------------------------------------------- pooling ---
__global__ __launch_bounds__(256) void count_nodes(const int* __restrict__ gid,
                                                   float* __restrict__ cnt) {
    int t = blockIdx.x * 256 + threadIdx.x;
    if (t < NN) atomicAdd(&cnt[gid[t]], 1.0f);
}

__global__ __launch_bounds__(256) void pool_sum(const float* __restrict__ h,
                                                const int* __restrict__ gid,
                                                float* __restrict__ hg) {
    int tid = threadIdx.x;
    int c = tid & 127;
    int grp = tid >> 7;
    int n0 = blockIdx.x * 64 + grp * 32;
    float acc = 0.f;
    int gcur = -1;
    for (int i = 0; i < 32; ++i) {
        int n = n0 + i;
        if (n >= NN) break;
        int g = gid[n];
        if (g != gcur) {
            if (gcur >= 0) atomicAdd(&hg[gcur * DHID + c], acc);
            gcur = g;
            acc = 0.f;
        }
        acc += h[(size_t)n * DHID + c];
    }
    if (gcur >= 0) atomicAdd(&hg[gcur * DHID + c], acc);
}

// ------------------------------------------------------------- classifier ---
__global__ __launch_bounds__(256) void classifier_k(const float* __restrict__ hg,
                                                    const float* __restrict__ cnt,
                                                    const float* __restrict__ Wc,
                                                    const float* __restrict__ bc,
                                                    float* __restrict__ out) {
    int t = blockIdx.x * 256 + threadIdx.x;
    if (t >= GG * NCLS) return;
    int g = t / NCLS;
    int c = t - g * NCLS;
    float inv = 1.0f / fmaxf(cnt[g], 1.0f);
    float acc = 0.f;
    #pragma unroll 4
    for (int k = 0; k < DHID; ++k)
        acc = fmaf(hg[g * DHID + k], Wc[k * NCLS + c], acc);
    out[t] = acc * inv + bc[c];
}

// ---------------------------------------------------------------- launch ----
extern "C" void kernel_launch(void* const* d_in, const int* in_sizes, int n_in,
                              void* d_out, int out_size, void* d_ws, size_t ws_size,
                              hipStream_t stream) {
    const float* features = (const float*)d_in[0];
    const int*   edges    = (const int*)d_in[1];
    const int*   gid      = (const int*)d_in[2];
    const float* W0       = (const float*)d_in[3];
    const float* b0       = (const float*)d_in[4];
    const float* Wl       = (const float*)d_in[5];
    const float* bl       = (const float*)d_in[6];
    const float* Wc       = (const float*)d_in[7];
    const float* bc       = (const float*)d_in[8];
    float* out = (float*)d_out;

    // ---- workspace carve-up ----
    int* iw = (int*)d_ws;
    size_t off = 0;
    int* cnt_out = iw + off; off += RN;
    int* cnt_in  = iw + off; off += RN;
    int* row_ptr = iw + off; off += RN + 1;
    int* cursor  = iw + off; off += RN;
    int* partial = iw + off; off += 512;
    off = (off + 3) & ~(size_t)3;            // 16B align for int2/float4 users
    int2* ew     = (int2*)(iw + off); off += (size_t)2 * RR * NE;
    float* fw = (float*)(iw + off);
    size_t foff = 0;
    float* so   = fw + foff; foff += RN;
    float* si   = fw + foff; foff += RN;
    float* hA   = fw + foff; foff += (size_t)NN * DHID;
    float* hB   = fw + foff; foff += (size_t)NN * DHID;
    float* hg   = fw + foff; foff += (size_t)GG * DHID;
    float* cntg = fw + foff; foff += GG;
    if (ws_size < (off + foff) * sizeof(int)) return;

    // ---- degrees, scales, CSR (edges constant -> rebuild each call) ----
    hipMemsetAsync(cnt_out, 0, (size_t)2 * RN * sizeof(int), stream);
    degree_count<<<(RR * NE + 255) / 256, 256, 0, stream>>>(edges, cnt_out, cnt_in);
    deg_to_scale<<<(RN + 255) / 256, 256, 0, stream>>>(cnt_out, cnt_in, so, si);
    scan_partial<<<NBLK, 256, 0, stream>>>(cnt_in, partial);
    scan_block<<<1, 512, 0, stream>>>(partial);
    scan_write<<<NBLK, 256, 0, stream>>>(cnt_in, partial, row_ptr, cursor);
    fill_csr<<<(RR * NE + 255) / 256, 256, 0, stream>>>(edges, so, si, cursor, ew);

    // ---- 3 fused layers ----
    for (int l = 0; l < 3; ++l) {
        const float* hin  = (l == 0) ? features : ((l == 1) ? hA : hB);
        float*       hout = (l == 0) ? hA : ((l == 1) ? hB : hA);
        const float* Wp   = (l == 0) ? W0 : Wl + (size_t)(l - 1) * RR * DHID * DHID;
        const float* bp   = (l == 0) ? b0 : bl + (size_t)(l - 1) * RR * DHID;
        layer_kernel<<<(NN + 31) / 32, 256, 0, stream>>>(
            hin, row_ptr, ew, Wp, bp, hout);
    }

    // ---- pooling + classifier ----
    hipMemsetAsync(hg, 0, ((size_t)GG * DHID + GG) * sizeof(float), stream);
    count_nodes<<<(NN + 255) / 256, 256, 0, stream>>>(gid, cntg);
    pool_sum<<<(NN + 63) / 64, 256, 0, stream>>>(hA, gid, hg);
    classifier_k<<<(GG * NCLS + 255) / 256, 256, 0, stream>>>(hg, cntg, Wc, bc, out);
}

// Round 4
// 2410.476 us; speedup vs baseline: 1.5322x; 1.5322x over previous
//
#include <hip/hip_runtime.h>

#define NN 100000      // nodes
#define NE 1000000     // edges per relation
#define RR 4           // relations
#define GG 256         // graphs
#define DHID 128       // feature width (DIN == DH == 128)
#define NCLS 10        // classes
#define RN (RR * NN)   // virtual segments (r, dst)
#define NBLK ((RN + 1023) / 1024)
#define HBW 64         // packed bf16 row width in uints (128 bf16)

// ---- bf16 helpers (packed 2 per uint; low ushort = even col) ----
__device__ __forceinline__ float bflo(unsigned v) { return __int_as_float((int)(v << 16)); }
__device__ __forceinline__ float bfhi(unsigned v) { return __int_as_float((int)(v & 0xffff0000u)); }
__device__ __forceinline__ unsigned pack_bf2(float a, float b) {
    unsigned ua = __float_as_uint(a), ub = __float_as_uint(b);
    ua = (ua + 0x7fffu + ((ua >> 16) & 1u)) >> 16;     // round-to-nearest-even
    ub = (ub + 0x7fffu + ((ub >> 16) & 1u)) >> 16;
    return ua | (ub << 16);
}

// ---------------------------------------------------------------- degrees ---
__global__ __launch_bounds__(256) void degree_count(const int* __restrict__ edges,
                                                    int* __restrict__ cnt_out,
                                                    int* __restrict__ cnt_in) {
    int t = blockIdx.x * 256 + threadIdx.x;
    if (t >= RR * NE) return;
    int r = t / NE;
    int e = t - r * NE;
    const int* base = edges + (size_t)r * 2 * NE;
    atomicAdd(&cnt_out[r * NN + base[e]], 1);
    atomicAdd(&cnt_in[r * NN + base[NE + e]], 1);
}

__global__ __launch_bounds__(256) void deg_to_scale(const int* __restrict__ cnt_out,
                                                    const int* __restrict__ cnt_in,
                                                    float* __restrict__ so,
                                                    float* __restrict__ si) {
    int t = blockIdx.x * 256 + threadIdx.x;
    if (t >= RN) return;
    int co = cnt_out[t], ci = cnt_in[t];
    so[t] = rsqrtf((float)(co < 1 ? 1 : co));
    si[t] = rsqrtf((float)(ci < 1 ? 1 : ci));
}

// ------------------------------------------------------------- CSR build ----
__global__ __launch_bounds__(256) void scan_partial(const int* __restrict__ cnt,
                                                    int* __restrict__ partial) {
    __shared__ int sdat[256];
    int t = threadIdx.x;
    int base = blockIdx.x * 1024 + t * 4;
    int s = 0;
    #pragma unroll
    for (int i = 0; i < 4; ++i)
        if (base + i < RN) s += cnt[base + i];
    sdat[t] = s;
    __syncthreads();
    for (int off = 128; off > 0; off >>= 1) {
        if (t < off) sdat[t] += sdat[t + off];
        __syncthreads();
    }
    if (t == 0) partial[blockIdx.x] = sdat[0];
}

__global__ __launch_bounds__(512) void scan_block(int* __restrict__ partial) {
    __shared__ int s[512];
    int t = threadIdx.x;
    s[t] = (t < NBLK) ? partial[t] : 0;
    __syncthreads();
    for (int off = 1; off < 512; off <<= 1) {
        int v = (t >= off) ? s[t - off] : 0;
        __syncthreads();
        s[t] += v;
        __syncthreads();
    }
    if (t < NBLK) partial[t] = (t == 0) ? 0 : s[t - 1];
}

__global__ __launch_bounds__(256) void scan_write(const int* __restrict__ cnt,
                                                  const int* __restrict__ partial,
                                                  int* __restrict__ row_ptr,
                                                  int* __restrict__ cursor) {
    __shared__ int ssum[256];
    int t = threadIdx.x;
    int base = blockIdx.x * 1024 + t * 4;
    int c[4];
    #pragma unroll
    for (int i = 0; i < 4; ++i)
        c[i] = (base + i < RN) ? cnt[base + i] : 0;
    ssum[t] = c[0] + c[1] + c[2] + c[3];
    __syncthreads();
    for (int off = 1; off < 256; off <<= 1) {
        int v = (t >= off) ? ssum[t - off] : 0;
        __syncthreads();
        ssum[t] += v;
        __syncthreads();
    }
    int e = partial[blockIdx.x] + (t == 0 ? 0 : ssum[t - 1]);
    #pragma unroll
    for (int i = 0; i < 4; ++i) {
        if (base + i < RN) { row_ptr[base + i] = e; cursor[base + i] = e; e += c[i]; }
    }
    if (blockIdx.x == 0 && t == 0) row_ptr[RN] = RR * NE;
}

// packed edge record: .x = src index, .y = float bits of so[src]*si[dst]
__global__ __launch_bounds__(256) void fill_csr(const int* __restrict__ edges,
                                                const float* __restrict__ so,
                                                const float* __restrict__ si,
                                                int* __restrict__ cursor,
                                                int2* __restrict__ ew) {
    int t = blockIdx.x * 256 + threadIdx.x;
    if (t >= RR * NE) return;
    int r = t / NE;
    int e = t - r * NE;
    const int* eb = edges + (size_t)r * 2 * NE;
    int s = eb[e];
    int d = eb[NE + e];
    int rb = r * NN;
    float w = so[rb + s] * si[rb + d];
    int pos = atomicAdd(&cursor[rb + d], 1);
    ew[pos] = make_int2(s, __float_as_int(w));
}

// ------------------------------------------------------------- f32 -> bf16 --
__global__ __launch_bounds__(256) void f32_to_bf16(const float* __restrict__ in,
                                                   unsigned* __restrict__ out) {
    int t = blockIdx.x * 256 + threadIdx.x;
    if (t >= NN * DHID / 4) return;
    float4 v = ((const float4*)in)[t];
    uint2 o;
    o.x = pack_bf2(v.x, v.y);
    o.y = pack_bf2(v.z, v.w);
    ((uint2*)out)[t] = o;
}

// ------------------------------------------------------------- layer --------
// One kernel = one full HeteroGraphConv layer + bias + ReLU (bf16 h storage).
// 64-row tile, As in LDS as bf16 (16.9KB). Per relation: gather (4-deep,
// prefolded weights, bf16 rows = 256B) -> As; GEMM acc += As @ W_r with
// 4 rows x 8 cols per thread (rows strided 16). Epilogue: +sum_r b, ReLU,
// pack bf16, ushort8 store.
__global__ __launch_bounds__(256) void layer_kernel(
    const unsigned* __restrict__ hb, const int* __restrict__ row_ptr,
    const int2* __restrict__ ew, const float* __restrict__ W,
    const float* __restrict__ b, unsigned* __restrict__ hbout) {
    __shared__ unsigned short As[64 * 132];   // bf16 tile, row stride 132
    const int tid  = threadIdx.x;
    const int wave = tid >> 6;
    const int lane = tid & 63;
    const int rowbase = blockIdx.x * 64;

    const int rt = tid & 15;          // row thread: owns rows rt+16m
    const int ct = tid >> 4;          // col thread: owns cols ct*8..ct*8+7

    float acc[4][8];
    #pragma unroll
    for (int m = 0; m < 4; ++m)
        #pragma unroll
        for (int i = 0; i < 8; ++i) acc[m][i] = 0.f;

    for (int r = 0; r < RR; ++r) {
        const int rbase = r * NN;
        if (r) __syncthreads();       // previous GEMM done reading As

        // ---- gather: wave owns 16 rows; control flow wave-uniform ----
        for (int rr = 0; rr < 16; ++rr) {
            int rowLocal = wave * 16 + rr;
            int d = rowbase + rowLocal;
            float ax = 0.f, ay = 0.f;
            if (d < NN) {
                int beg = row_ptr[rbase + d];
                int end = row_ptr[rbase + d + 1];
                int j = beg;
                for (; j + 4 <= end; j += 4) {
                    int2 p0 = ew[j], p1 = ew[j + 1], p2 = ew[j + 2], p3 = ew[j + 3];
                    unsigned v0 = hb[p0.x * HBW + lane];
                    unsigned v1 = hb[p1.x * HBW + lane];
                    unsigned v2 = hb[p2.x * HBW + lane];
                    unsigned v3 = hb[p3.x * HBW + lane];
                    float w0 = __int_as_float(p0.y), w1 = __int_as_float(p1.y);
                    float w2 = __int_as_float(p2.y), w3 = __int_as_float(p3.y);
                    ax = fmaf(w0, bflo(v0), ax); ay = fmaf(w0, bfhi(v0), ay);
                    ax = fmaf(w1, bflo(v1), ax); ay = fmaf(w1, bfhi(v1), ay);
                    ax = fmaf(w2, bflo(v2), ax); ay = fmaf(w2, bfhi(v2), ay);
                    ax = fmaf(w3, bflo(v3), ax); ay = fmaf(w3, bfhi(v3), ay);
                }
                for (; j < end; ++j) {
                    int2 p = ew[j];
                    unsigned v = hb[p.x * HBW + lane];
                    float w = __int_as_float(p.y);
                    ax = fmaf(w, bflo(v), ax); ay = fmaf(w, bfhi(v), ay);
                }
            }
            *(unsigned*)&As[rowLocal * 132 + 2 * lane] = pack_bf2(ax, ay);
        }
        __syncthreads();

        // ---- GEMM: acc[m][*] += As[rt+16m][:] @ W_r[:, ct*8..+7] ----
        const float4* Wv = (const float4*)(W + (size_t)r * DHID * DHID);
        for (int k = 0; k < 128; k += 4) {
            uint2 au[4];
            #pragma unroll
            for (int m = 0; m < 4; ++m)
                au[m] = *(const uint2*)&As[(rt + 16 * m) * 132 + k];
            float a[4][4];
            #pragma unroll
            for (int m = 0; m < 4; ++m) {
                a[m][0] = bflo(au[m].x); a[m][1] = bfhi(au[m].x);
                a[m][2] = bflo(au[m].y); a[m][3] = bfhi(au[m].y);
            }
            #pragma unroll
            for (int kk = 0; kk < 4; ++kk) {
                float4 w0 = Wv[(k + kk) * 32 + ct * 2];
                float4 w1 = Wv[(k + kk) * 32 + ct * 2 + 1];
                #pragma unroll
                for (int m = 0; m < 4; ++m) {
                    float x = a[m][kk];
                    acc[m][0] = fmaf(x, w0.x, acc[m][0]);
                    acc[m][1] = fmaf(x, w0.y, acc[m][1]);
                    acc[m][2] = fmaf(x, w0.z, acc[m][2]);
                    acc[m][3] = fmaf(x, w0.w, acc[m][3]);
                    acc[m][4] = fmaf(x, w1.x, acc[m][4]);
                    acc[m][5] = fmaf(x, w1.y, acc[m][5]);
                    acc[m][6] = fmaf(x, w1.z, acc[m][6]);
                    acc[m][7] = fmaf(x, w1.w, acc[m][7]);
                }
            }
        }
    }

    // ---- epilogue: + sum_r b[r], ReLU, pack bf16, store ----
    float bsum[8];
    #pragma unroll
    for (int i = 0; i < 8; ++i) {
        int col = ct * 8 + i;
        bsum[i] = b[0 * DHID + col] + b[1 * DHID + col] +
                  b[2 * DHID + col] + b[3 * DHID + col];
    }
    #pragma unroll
    for (int m = 0; m < 4; ++m) {
        int row = rowbase + rt + 16 * m;
        if (row < NN) {
            float o[8];
            #pragma unroll
            for (int i = 0; i < 8; ++i)
                o[i] = fmaxf(acc[m][i] + bsum[i], 0.f);
            uint4 pk;
            pk.x = pack_bf2(o[0], o[1]);
            pk.y = pack_bf2(o[2], o[3]);
            pk.z = pack_bf2(o[4], o[5]);
            pk.w = pack_bf2(o[6], o[7]);
            *(uint4*)&hbout[(size_t)row * HBW + ct * 4] = pk;
        }
    }
}

// ---------------------------------------------------------------- pooling ---
__global__ __launch_bounds__(256) void count_nodes(const int* __restrict__ gid,
                                                   float* __restrict__ cnt) {
    int t = blockIdx.x * 256 + threadIdx.x;
    if (t < NN) atomicAdd(&cnt[gid[t]], 1.0f);
}

__global__ __launch_bounds__(256) void pool_sum_bf(const unsigned* __restrict__ hb,
                                                   const int* __restrict__ gid,
                                                   float* __restrict__ hg) {
    int tid = threadIdx.x;
    int c = tid & 63;                  // uint column (2 features)
    int grp = tid >> 6;                // 4 groups x 16 nodes
    int n0 = blockIdx.x * 64 + grp * 16;
    float ax = 0.f, ay = 0.f;
    int gcur = -1;
    for (int i = 0; i < 16; ++i) {
        int n = n0 + i;
        if (n >= NN) break;
        int g = gid[n];
        if (g != gcur) {
            if (gcur >= 0) {
                atomicAdd(&hg[gcur * DHID + 2 * c], ax);
                atomicAdd(&hg[gcur * DHID + 2 * c + 1], ay);
            }
            gcur = g;
            ax = ay = 0.f;
        }
        unsigned v = hb[(size_t)n * HBW + c];
        ax += bflo(v); ay += bfhi(v);
    }
    if (gcur >= 0) {
        atomicAdd(&hg[gcur * DHID + 2 * c], ax);
        atomicAdd(&hg[gcur * DHID + 2 * c + 1], ay);
    }
}

// ------------------------------------------------------------- classifier ---
__global__ __launch_bounds__(256) void classifier_k(const float* __restrict__ hg,
                                                    const float* __restrict__ cnt,
                                                    const float* __restrict__ Wc,
                                                    const float* __restrict__ bc,
                                                    float* __restrict__ out) {
    int t = blockIdx.x * 256 + threadIdx.x;
    if (t >= GG * NCLS) return;
    int g = t / NCLS;
    int c = t - g * NCLS;
    float inv = 1.0f / fmaxf(cnt[g], 1.0f);
    float acc = 0.f;
    #pragma unroll 4
    for (int k = 0; k < DHID; ++k)
        acc = fmaf(hg[g * DHID + k], Wc[k * NCLS + c], acc);
    out[t] = acc * inv + bc[c];
}

// ---------------------------------------------------------------- launch ----
extern "C" void kernel_launch(void* const* d_in, const int* in_sizes, int n_in,
                              void* d_out, int out_size, void* d_ws, size_t ws_size,
                              hipStream_t stream) {
    const float* features = (const float*)d_in[0];
    const int*   edges    = (const int*)d_in[1];
    const int*   gid      = (const int*)d_in[2];
    const float* W0       = (const float*)d_in[3];
    const float* b0       = (const float*)d_in[4];
    const float* Wl       = (const float*)d_in[5];
    const float* bl       = (const float*)d_in[6];
    const float* Wc       = (const float*)d_in[7];
    const float* bc       = (const float*)d_in[8];
    float* out = (float*)d_out;

    // ---- workspace carve-up ----
    int* iw = (int*)d_ws;
    size_t off = 0;
    int* cnt_out = iw + off; off += RN;
    int* cnt_in  = iw + off; off += RN;
    int* row_ptr = iw + off; off += RN + 1;
    int* cursor  = iw + off; off += RN;
    int* partial = iw + off; off += 512;
    off = (off + 3) & ~(size_t)3;            // 16B align
    int2* ew     = (int2*)(iw + off); off += (size_t)2 * RR * NE;
    float* so    = (float*)(iw + off); off += RN;
    float* si    = (float*)(iw + off); off += RN;
    float* hg    = (float*)(iw + off); off += (size_t)GG * DHID;
    float* cntg  = (float*)(iw + off); off += GG;
    off = (off + 3) & ~(size_t)3;
    unsigned* hb0 = (unsigned*)(iw + off); off += (size_t)NN * HBW;
    unsigned* hbA = (unsigned*)(iw + off); off += (size_t)NN * HBW;
    unsigned* hbB = (unsigned*)(iw + off); off += (size_t)NN * HBW;
    if (ws_size < off * sizeof(int)) return;

    // ---- degrees, scales, CSR (edges constant -> rebuild each call) ----
    hipMemsetAsync(cnt_out, 0, (size_t)2 * RN * sizeof(int), stream);
    degree_count<<<(RR * NE + 255) / 256, 256, 0, stream>>>(edges, cnt_out, cnt_in);
    deg_to_scale<<<(RN + 255) / 256, 256, 0, stream>>>(cnt_out, cnt_in, so, si);
    scan_partial<<<NBLK, 256, 0, stream>>>(cnt_in, partial);
    scan_block<<<1, 512, 0, stream>>>(partial);
    scan_write<<<NBLK, 256, 0, stream>>>(cnt_in, partial, row_ptr, cursor);
    fill_csr<<<(RR * NE + 255) / 256, 256, 0, stream>>>(edges, so, si, cursor, ew);

    // ---- features -> bf16 ----
    f32_to_bf16<<<(NN * DHID / 4 + 255) / 256, 256, 0, stream>>>(features, hb0);

    // ---- 3 fused layers (bf16 h storage) ----
    const unsigned* hin[3] = {hb0, hbA, hbB};
    unsigned*       hout_[3] = {hbA, hbB, hbA};
    for (int l = 0; l < 3; ++l) {
        const float* Wp = (l == 0) ? W0 : Wl + (size_t)(l - 1) * RR * DHID * DHID;
        const float* bp = (l == 0) ? b0 : bl + (size_t)(l - 1) * RR * DHID;
        layer_kernel<<<(NN + 63) / 64, 256, 0, stream>>>(
            hin[l], row_ptr, ew, Wp, bp, hout_[l]);
    }

    // ---- pooling + classifier ----
    hipMemsetAsync(hg, 0, ((size_t)GG * DHID + GG) * sizeof(float), stream);
    count_nodes<<<(NN + 255) / 256, 256, 0, stream>>>(gid, cntg);
    pool_sum_bf<<<(NN + 63) / 64, 256, 0, stream>>>(hbA, gid, hg);
    classifier_k<<<(GG * NCLS + 255) / 256, 256, 0, stream>>>(hg, cntg, Wc, bc, out);
}